// Round 5
// baseline (299.398 us; speedup 1.0000x reference)
//
#include <hip/hip_runtime.h>
#include <cstdint>

constexpr int N_FEAT  = 8;
constexpr int E_FEAT  = 4;
constexpr int NUM_IN  = 2 * (N_FEAT + 2) + E_FEAT + 1;  // 25
constexpr int NUM_OUT = 2 * N_FEAT + E_FEAT;            // 20
constexpr int BLK     = 256;

// Weight streaming via VMEM, not SMEM:
// Uniform weight addresses let the compiler use s_load -> SGPRs. SMEM returns
// are out-of-order, so every batch must be consumed behind s_waitcnt
// lgkmcnt(0) -- a full ~200-cy scalar-pipe drain per ~64-dword batch. That
// caps per-wave VALU utilization at ~40% (measured, invariant to spills and
// occupancy). Pinning the weight pointers into VGPRs with an empty asm makes
// them opaque/divergent -> global_load_dwordx4, in-order vmcnt, deep
// software pipelining by the compiler, L2-resident broadcast (4.5 KB total).
// W rows are 25 floats (100 B) so rows are not 16B-aligned; we stream each
// matrix as a FLAT float4 stream with compile-time (row=d/25, col=d%25)
// mapping: W1 = 156 float4 + 1 dword, W2 = exactly 125 float4.
__global__ __launch_bounds__(BLK)
__attribute__((amdgpu_waves_per_eu(3, 4)))
void edge_mlp(
    const float* __restrict__ r,
    const float* __restrict__ a_data,
    const float* __restrict__ a_mat,
    const float* __restrict__ a_inf,
    const float* __restrict__ b_data,
    const float* __restrict__ b_mat,
    const float* __restrict__ b_inf,
    const float* __restrict__ e_data,
    const float* __restrict__ W1,   // (25,25) row-major fp32
    const float* __restrict__ B1,   // (25,)
    const float* __restrict__ W2,   // (20,25) row-major
    const float* __restrict__ B2,   // (20,)
    float*       __restrict__ out,  // fp32, 3 segments concatenated
    int E) {
  const int e = blockIdx.x * BLK + threadIdx.x;
  if (e >= E) return;

  // Pin weight base pointers into VGPRs (see comment above).
  const float* W1v = W1;
  const float* W2v = W2;
  asm volatile("" : "+v"(W1v), "+v"(W2v));

  // ---- gather the 25 fp32 input features (round-0 proven-promoting form) ----
  const float4* a4 = reinterpret_cast<const float4*>(a_data) + 2 * (size_t)e;
  const float4* b4 = reinterpret_cast<const float4*>(b_data) + 2 * (size_t)e;
  float4 a0 = a4[0], a1 = a4[1];
  float4 b0 = b4[0], b1v = b4[1];
  float4 ev = reinterpret_cast<const float4*>(e_data)[e];

  float x[NUM_IN];
  x[0]  = r[e];
  x[1]  = a0.x; x[2]  = a0.y; x[3]  = a0.z; x[4]  = a0.w;
  x[5]  = a1.x; x[6]  = a1.y; x[7]  = a1.z; x[8]  = a1.w;
  x[9]  = a_mat[e];
  x[10] = a_inf[e];
  x[11] = b0.x; x[12] = b0.y; x[13] = b0.z; x[14] = b0.w;
  x[15] = b1v.x; x[16] = b1v.y; x[17] = b1v.z; x[18] = b1v.w;
  x[19] = b_mat[e];
  x[20] = b_inf[e];
  x[21] = ev.x; x[22] = ev.y; x[23] = ev.z; x[24] = ev.w;

  // ---- layer 1: acc = W1 @ x + b1, flat-float4 weight stream ----
  float acc[NUM_IN];
#pragma unroll
  for (int j = 0; j < NUM_IN; ++j) acc[j] = B1[j];   // biases: scalar path (45 dwords total, one-time)
  {
    const float4* w4 = reinterpret_cast<const float4*>(W1v);
#pragma unroll
    for (int i = 0; i < 156; ++i) {          // dwords 0..623
      const float4 w = w4[i];
      const int d = 4 * i;
      acc[(d + 0) / NUM_IN] = fmaf(w.x, x[(d + 0) % NUM_IN], acc[(d + 0) / NUM_IN]);
      acc[(d + 1) / NUM_IN] = fmaf(w.y, x[(d + 1) % NUM_IN], acc[(d + 1) / NUM_IN]);
      acc[(d + 2) / NUM_IN] = fmaf(w.z, x[(d + 2) % NUM_IN], acc[(d + 2) / NUM_IN]);
      acc[(d + 3) / NUM_IN] = fmaf(w.w, x[(d + 3) % NUM_IN], acc[(d + 3) / NUM_IN]);
    }
    acc[24] = fmaf(W1v[624], x[24], acc[24]);  // final dword (row 24, col 24)
  }
  float h[NUM_IN];
#pragma unroll
  for (int j = 0; j < NUM_IN; ++j) h[j] = fmaxf(acc[j], 0.0f);

  // ---- layer 2: acc2 = W2 @ h + b2, exactly 125 float4 ----
  float acc2[NUM_OUT];
#pragma unroll
  for (int j = 0; j < NUM_OUT; ++j) acc2[j] = B2[j];
  {
    const float4* w4 = reinterpret_cast<const float4*>(W2v);
#pragma unroll
    for (int i = 0; i < 125; ++i) {          // dwords 0..499
      const float4 w = w4[i];
      const int d = 4 * i;
      acc2[(d + 0) / NUM_IN] = fmaf(w.x, h[(d + 0) % NUM_IN], acc2[(d + 0) / NUM_IN]);
      acc2[(d + 1) / NUM_IN] = fmaf(w.y, h[(d + 1) % NUM_IN], acc2[(d + 1) / NUM_IN]);
      acc2[(d + 2) / NUM_IN] = fmaf(w.z, h[(d + 2) % NUM_IN], acc2[(d + 2) / NUM_IN]);
      acc2[(d + 3) / NUM_IN] = fmaf(w.w, h[(d + 3) % NUM_IN], acc2[(d + 3) / NUM_IN]);
    }
  }

  float y[NUM_OUT];
#pragma unroll
  for (int j = 0; j < NUM_OUT; ++j) y[j] = fmaxf(acc2[j], 0.0f);

  // ---- store fp32 into the 3 concatenated output segments ----
  float4* o0 = reinterpret_cast<float4*>(out) + 2 * (size_t)e;            // (E,8)
  o0[0] = make_float4(y[0], y[1], y[2],  y[3]);
  o0[1] = make_float4(y[4], y[5], y[6],  y[7]);
  float4* o1 = reinterpret_cast<float4*>(out + (size_t)8 * E) + 2 * (size_t)e;  // (E,8)
  o1[0] = make_float4(y[8],  y[9],  y[10], y[11]);
  o1[1] = make_float4(y[12], y[13], y[14], y[15]);
  reinterpret_cast<float4*>(out + (size_t)16 * E)[e] =                    // (E,4)
      make_float4(y[16], y[17], y[18], y[19]);
}

extern "C" void kernel_launch(void* const* d_in, const int* in_sizes, int n_in,
                              void* d_out, int out_size, void* d_ws, size_t ws_size,
                              hipStream_t stream) {
  const float* r      = (const float*)d_in[0];
  const float* a_data = (const float*)d_in[1];
  const float* a_mat  = (const float*)d_in[2];
  const float* a_inf  = (const float*)d_in[3];
  const float* b_data = (const float*)d_in[4];
  const float* b_mat  = (const float*)d_in[5];
  const float* b_inf  = (const float*)d_in[6];
  const float* e_data = (const float*)d_in[7];
  const float* W1     = (const float*)d_in[8];
  const float* B1     = (const float*)d_in[9];
  const float* W2     = (const float*)d_in[10];
  const float* B2     = (const float*)d_in[11];
  int E = in_sizes[0];

  edge_mlp<<<(E + BLK - 1) / BLK, BLK, 0, stream>>>(
      r, a_data, a_mat, a_inf, b_data, b_mat, b_inf, e_data,
      W1, B1, W2, B2, (float*)d_out, E);
}

// Round 6
// 195.720 us; speedup vs baseline: 1.5297x; 1.5297x over previous
//
#include <hip/hip_runtime.h>
#include <cstdint>

constexpr int N_FEAT  = 8;
constexpr int E_FEAT  = 4;
constexpr int NUM_IN  = 2 * (N_FEAT + 2) + E_FEAT + 1;  // 25
constexpr int NUM_OUT = 2 * N_FEAT + E_FEAT;            // 20
constexpr int BLK     = 256;

// Weight delivery, attempt 3: LDS broadcast.
//  - SMEM (s_load->SGPR) weights: out-of-order returns force s_waitcnt
//    lgkmcnt(0) full drains per SGPR batch -> 77 us, VALUBusy 40%.
//  - VMEM (global_load->VGPR) weights: in-order but ~200cy/instr latency,
//    281 loads/edge can't pipeline in 80 VGPRs -> 171 us, VALUBusy 19%.
//  - LDS: returns are IN-ORDER (compiler emits counted lgkmcnt(N), not
//    drains), latency ~120cy, and same-address-across-lanes reads are
//    conflict-free broadcasts. Weights staged once per block (4.7 KB),
//    amortized over 256 edges.
// W rows are 25 floats (100 B, not 16B-aligned) so we stream each matrix as
// a FLAT float4 stream with compile-time (row=d/25, col=d%25) mapping:
// W1 = 156 float4 + 1 dword, W2 = exactly 125 float4.
__global__ __launch_bounds__(BLK)
__attribute__((amdgpu_waves_per_eu(3, 4)))
void edge_mlp(
    const float* __restrict__ r,
    const float* __restrict__ a_data,
    const float* __restrict__ a_mat,
    const float* __restrict__ a_inf,
    const float* __restrict__ b_data,
    const float* __restrict__ b_mat,
    const float* __restrict__ b_inf,
    const float* __restrict__ e_data,
    const float* __restrict__ W1,   // (25,25) row-major fp32
    const float* __restrict__ B1,   // (25,)
    const float* __restrict__ W2,   // (20,25) row-major
    const float* __restrict__ B2,   // (20,)
    float*       __restrict__ out,  // fp32, 3 segments concatenated
    int E) {
  __shared__ __align__(16) float sW1[628];      // 625 used, padded for float4 view
  __shared__ __align__(16) float sW2[500];      // exactly 125 float4
  __shared__ float sB1[NUM_IN];
  __shared__ float sB2[NUM_OUT];

  const int tid = threadIdx.x;
  // ---- stage weights into LDS (coalesced, once per block) ----
#pragma unroll
  for (int i = tid; i < 625; i += BLK) sW1[i] = W1[i];
#pragma unroll
  for (int i = tid; i < 500; i += BLK) sW2[i] = W2[i];
  if (tid < NUM_IN)  sB1[tid] = B1[tid];
  if (tid < NUM_OUT) sB2[tid] = B2[tid];
  __syncthreads();

  const int e = blockIdx.x * BLK + tid;
  if (e >= E) return;

  // ---- gather the 25 fp32 input features (coalesced float4 loads) ----
  const float4* a4 = reinterpret_cast<const float4*>(a_data) + 2 * (size_t)e;
  const float4* b4 = reinterpret_cast<const float4*>(b_data) + 2 * (size_t)e;
  float4 a0 = a4[0], a1 = a4[1];
  float4 b0 = b4[0], b1v = b4[1];
  float4 ev = reinterpret_cast<const float4*>(e_data)[e];

  float x[NUM_IN];
  x[0]  = r[e];
  x[1]  = a0.x; x[2]  = a0.y; x[3]  = a0.z; x[4]  = a0.w;
  x[5]  = a1.x; x[6]  = a1.y; x[7]  = a1.z; x[8]  = a1.w;
  x[9]  = a_mat[e];
  x[10] = a_inf[e];
  x[11] = b0.x; x[12] = b0.y; x[13] = b0.z; x[14] = b0.w;
  x[15] = b1v.x; x[16] = b1v.y; x[17] = b1v.z; x[18] = b1v.w;
  x[19] = b_mat[e];
  x[20] = b_inf[e];
  x[21] = ev.x; x[22] = ev.y; x[23] = ev.z; x[24] = ev.w;

  // ---- layer 1: acc = W1 @ x + b1, flat-float4 broadcast stream from LDS ----
  float acc[NUM_IN];
#pragma unroll
  for (int j = 0; j < NUM_IN; ++j) acc[j] = sB1[j];
  {
    const float4* w4 = reinterpret_cast<const float4*>(sW1);
#pragma unroll
    for (int i = 0; i < 156; ++i) {          // dwords 0..623
      const float4 w = w4[i];
      const int d = 4 * i;
      acc[(d + 0) / NUM_IN] = fmaf(w.x, x[(d + 0) % NUM_IN], acc[(d + 0) / NUM_IN]);
      acc[(d + 1) / NUM_IN] = fmaf(w.y, x[(d + 1) % NUM_IN], acc[(d + 1) / NUM_IN]);
      acc[(d + 2) / NUM_IN] = fmaf(w.z, x[(d + 2) % NUM_IN], acc[(d + 2) / NUM_IN]);
      acc[(d + 3) / NUM_IN] = fmaf(w.w, x[(d + 3) % NUM_IN], acc[(d + 3) / NUM_IN]);
    }
    acc[24] = fmaf(sW1[624], x[24], acc[24]);  // final dword (row 24, col 24)
  }
  float h[NUM_IN];
#pragma unroll
  for (int j = 0; j < NUM_IN; ++j) h[j] = fmaxf(acc[j], 0.0f);

  // ---- layer 2: acc2 = W2 @ h + b2, exactly 125 float4 from LDS ----
  float acc2[NUM_OUT];
#pragma unroll
  for (int j = 0; j < NUM_OUT; ++j) acc2[j] = sB2[j];
  {
    const float4* w4 = reinterpret_cast<const float4*>(sW2);
#pragma unroll
    for (int i = 0; i < 125; ++i) {          // dwords 0..499
      const float4 w = w4[i];
      const int d = 4 * i;
      acc2[(d + 0) / NUM_IN] = fmaf(w.x, h[(d + 0) % NUM_IN], acc2[(d + 0) / NUM_IN]);
      acc2[(d + 1) / NUM_IN] = fmaf(w.y, h[(d + 1) % NUM_IN], acc2[(d + 1) / NUM_IN]);
      acc2[(d + 2) / NUM_IN] = fmaf(w.z, h[(d + 2) % NUM_IN], acc2[(d + 2) / NUM_IN]);
      acc2[(d + 3) / NUM_IN] = fmaf(w.w, h[(d + 3) % NUM_IN], acc2[(d + 3) / NUM_IN]);
    }
  }

  float y[NUM_OUT];
#pragma unroll
  for (int j = 0; j < NUM_OUT; ++j) y[j] = fmaxf(acc2[j], 0.0f);

  // ---- store fp32 into the 3 concatenated output segments ----
  float4* o0 = reinterpret_cast<float4*>(out) + 2 * (size_t)e;            // (E,8)
  o0[0] = make_float4(y[0], y[1], y[2],  y[3]);
  o0[1] = make_float4(y[4], y[5], y[6],  y[7]);
  float4* o1 = reinterpret_cast<float4*>(out + (size_t)8 * E) + 2 * (size_t)e;  // (E,8)
  o1[0] = make_float4(y[8],  y[9],  y[10], y[11]);
  o1[1] = make_float4(y[12], y[13], y[14], y[15]);
  reinterpret_cast<float4*>(out + (size_t)16 * E)[e] =                    // (E,4)
      make_float4(y[16], y[17], y[18], y[19]);
}

extern "C" void kernel_launch(void* const* d_in, const int* in_sizes, int n_in,
                              void* d_out, int out_size, void* d_ws, size_t ws_size,
                              hipStream_t stream) {
  const float* r      = (const float*)d_in[0];
  const float* a_data = (const float*)d_in[1];
  const float* a_mat  = (const float*)d_in[2];
  const float* a_inf  = (const float*)d_in[3];
  const float* b_data = (const float*)d_in[4];
  const float* b_mat  = (const float*)d_in[5];
  const float* b_inf  = (const float*)d_in[6];
  const float* e_data = (const float*)d_in[7];
  const float* W1     = (const float*)d_in[8];
  const float* B1     = (const float*)d_in[9];
  const float* W2     = (const float*)d_in[10];
  const float* B2     = (const float*)d_in[11];
  int E = in_sizes[0];

  edge_mlp<<<(E + BLK - 1) / BLK, BLK, 0, stream>>>(
      r, a_data, a_mat, a_inf, b_data, b_mat, b_inf, e_data,
      W1, B1, W2, B2, (float*)d_out, E);
}